// Round 6
// baseline (159.424 us; speedup 1.0000x reference)
//
#include <hip/hip_runtime.h>
#include <hip/hip_bf16.h>
#include <stdint.h>

typedef __bf16 bf16;
typedef __bf16 bf16x8 __attribute__((ext_vector_type(8)));
typedef float f32x4 __attribute__((ext_vector_type(4)));

#define GAS __attribute__((address_space(1)))
#define LAS __attribute__((address_space(3)))

static constexpr int M = 4096;   // batch
static constexpr int N = 2048;   // 2C
static constexpr int K = 2048;   // 2C

static constexpr int BM = 128, BN = 256, BK = 64;
static constexpr int NT = K / BK;               // 32 K-tiles
static constexpr int A_ELE = BM * BK;           // 8192 bf16 = 16 KB
static constexpr int B_ELE = BN * BK;           // 16384 bf16 = 32 KB
static constexpr int BUF_ELE = A_ELE + B_ELE;   // 48 KB; x3 = 144 KB LDS

// --- async global->LDS, 16B per lane, dest = wave-uniform base + lane*16 ---
__device__ __forceinline__ void gload_lds16(const bf16* gsrc, bf16* ldst) {
    __builtin_amdgcn_global_load_lds((const GAS void*)gsrc, (LAS void*)ldst, 16, 0, 0);
}

// --- merged prep: pack concat(x0,x1)->bf16  +  3x W[K][N]fp32 -> Wt[N][K]bf16 ---
__global__ __launch_bounds__(256) void prep_kernel(const float* __restrict__ x0,
                                                   const float* __restrict__ x1,
                                                   const float* __restrict__ W0,
                                                   const float* __restrict__ W1,
                                                   const float* __restrict__ W2,
                                                   bf16* __restrict__ A,
                                                   bf16* __restrict__ Wt0,
                                                   bf16* __restrict__ Wt1,
                                                   bf16* __restrict__ Wt2) {
    __shared__ bf16 tile[32][33];
    int bid = blockIdx.x;
    int tid = threadIdx.x;
    if (bid < 4096) {
        // pack: 8 elems/thread; 8-chunks never straddle the 1024 seam
        int idx = (bid * 256 + tid) * 8;
        int b = idx >> 11;
        int c = idx & 2047;
        const float* src = (c < 1024) ? (x0 + (size_t)b * 1024 + c)
                                      : (x1 + (size_t)b * 1024 + (c - 1024));
        float4 v0 = *reinterpret_cast<const float4*>(src);
        float4 v1 = *reinterpret_cast<const float4*>(src + 4);
        bf16x8 o;
        o[0] = (bf16)v0.x; o[1] = (bf16)v0.y; o[2] = (bf16)v0.z; o[3] = (bf16)v0.w;
        o[4] = (bf16)v1.x; o[5] = (bf16)v1.y; o[6] = (bf16)v1.z; o[7] = (bf16)v1.w;
        *reinterpret_cast<bf16x8*>(A + idx) = o;
    } else {
        int r = bid - 4096;
        int w = r >> 12;                 // which W (4096 tiles each)
        int t = r & 4095;
        const float* W  = (w == 0) ? W0  : (w == 1) ? W1  : W2;
        bf16*        Wt = (w == 0) ? Wt0 : (w == 1) ? Wt1 : Wt2;
        int n0 = (t & 63) * 32;
        int k0 = (t >> 6) * 32;
        int tx = tid & 31;
        int ty = tid >> 5;
        #pragma unroll
        for (int i = 0; i < 4; i++) {
            int k = ty + i * 8;
            tile[k][tx] = (bf16)W[(size_t)(k0 + k) * N + n0 + tx];
        }
        __syncthreads();
        #pragma unroll
        for (int i = 0; i < 4; i++) {
            int n = ty + i * 8;
            Wt[(size_t)(n0 + n) * K + k0 + tx] = tile[tx][n];   // Wt[n][k] = W[k][n]
        }
    }
}

__device__ __forceinline__ void read_a(const bf16* __restrict__ ba, int aoff, int slot, bf16x8 af[4]) {
    #pragma unroll
    for (int mi = 0; mi < 4; mi++)
        af[mi] = *reinterpret_cast<const bf16x8*>(ba + aoff + mi * 1024 + slot);
}
__device__ __forceinline__ void read_b(const bf16* __restrict__ bb, int boff, int slot, bf16x8 bv[8]) {
    #pragma unroll
    for (int ni = 0; ni < 8; ni++)
        bv[ni] = *reinterpret_cast<const bf16x8*>(bb + boff + ni * 1024 + slot);
}

__device__ __forceinline__ void do_mfma32(const bf16x8 af[4], const bf16x8 bv[8], f32x4 acc[4][8]) {
    __builtin_amdgcn_s_setprio(1);
    #pragma unroll
    for (int mi = 0; mi < 4; mi++)
        #pragma unroll
        for (int ni = 0; ni < 8; ni++)
            acc[mi][ni] = __builtin_amdgcn_mfma_f32_16x16x32_bf16(af[mi], bv[ni], acc[mi][ni], 0, 0, 0);
    __builtin_amdgcn_s_setprio(0);
}

// --- 128x256-tile bf16 GEMM, 4 waves (2Mx2N, 64x128/wave): LDS-traffic-minimized.
//     Per CU per K-tile: 96 KB ds_read (was 128 KB with 8 waves) + 48 KB gload writes
//     => LDS pipe ~1500 cyc ~ MFMA 1242 cyc. 3 rotating buffers, depth-2 prefetch,
//     vmcnt(12) steady-state, T2 swizzle, 1 barrier/tile, lgkm(12)-split. ---
template <bool OUT_BF16>
__global__ __launch_bounds__(256, 1) void gemm4w_kernel(const bf16* __restrict__ A,   // [M][K]
                                                        const bf16* __restrict__ Bt,  // [N][K]
                                                        void* __restrict__ Cout) {    // [M][N]
    __shared__ bf16 lds[3 * BUF_ELE];   // 144 KB

    // XCD-aware bijective swizzle (256 blocks, 256 % 8 == 0)
    int bid = blockIdx.x;
    int cpx = gridDim.x >> 3;
    int swz = (bid & 7) * cpx + (bid >> 3);
    int tm = swz >> 3;                           // 0..31
    int tn = swz & 7;                            // 0..7

    int tid  = threadIdx.x;
    int wave = tid >> 6;        // 0..3
    int lane = tid & 63;
    int wr = wave >> 1;         // 0..1  (M half, 64 rows)
    int wc = wave & 1;          // 0..1  (N half, 128 cols)
    int fr = lane & 15;
    int fb = lane >> 4;

    // staging geometry: 256 threads cover 32 rows x 64 cols per gload (4 KB).
    // thread -> row tid>>3 (of 32), 16B slot tid&7; T2: global source col pre-swizzled.
    int srow = tid >> 3;                                   // 0..31
    int scol = ((tid & 7) ^ (srow & 7)) * 8;               // bf16 col within BK
    const bf16* aS = A  + (size_t)(tm * BM + srow) * K + scol;
    const bf16* bS = Bt + (size_t)(tn * BN + srow) * K + scol;
    int sdst = wave * 512;                                 // elems; HW adds lane*16B

    // read geometry: LDS slot = gslot ^ (row&7), row&7 == fr&7
    int aoff  = (wr * 64 + fr) * 64;
    int boff  = (wc * 128 + fr) * 64;
    int slot0 = ((fb) ^ (fr & 7)) * 8;                     // ks=0
    int slot1 = ((4 | fb) ^ (fr & 7)) * 8;                 // ks=1

    f32x4 acc[4][8] = {};

    auto STAGE = [&](int bi, int t) {                       // 12 gloads: A 4 chunks, B 8 chunks
        bf16* ba = (bf16*)lds + bi * BUF_ELE;
        bf16* bb = ba + A_ELE;
        const bf16* a = aS + t * BK;
        const bf16* b = bS + t * BK;
        #pragma unroll
        for (int c = 0; c < 4; c++)
            gload_lds16(a + (size_t)c * 32 * K, ba + sdst + c * 2048);
        #pragma unroll
        for (int c = 0; c < 8; c++)
            gload_lds16(b + (size_t)c * 32 * K, bb + sdst + c * 2048);
    };

    // ---- prologue: tiles 0,1 staged; tile 0 resident after barrier ----
    STAGE(0, 0);
    STAGE(1, 1);
    asm volatile("s_waitcnt vmcnt(12)" ::: "memory");
    __builtin_amdgcn_s_barrier();

    bf16x8 af0[4], bv0[8], af1[4], bv1[8];
    int cur = 0;
    // ---- main loop: one barrier per K-tile ----
    for (int t = 0; t < NT - 2; ++t) {
        const bf16* ba = (const bf16*)lds + cur * BUF_ELE;
        const bf16* bb = ba + A_ELE;
        int sb = cur + 2; if (sb >= 3) sb -= 3;

        read_a(ba, aoff, slot0, af0);                      // 12 ds_read (ks0)
        read_b(bb, boff, slot0, bv0);
        STAGE(sb, t + 2);                                  // 12 gloads (tile t+2)
        read_a(ba, aoff, slot1, af1);                      // 12 ds_read (ks1)
        read_b(bb, boff, slot1, bv1);
        asm volatile("s_waitcnt lgkmcnt(12)" ::: "memory"); // ks0 frags resident (DS in-order)
        __builtin_amdgcn_sched_barrier(0);
        do_mfma32(af0, bv0, acc);                          // ks1 reads + gloads land under 32 MFMAs
        asm volatile("s_waitcnt lgkmcnt(0)" ::: "memory");
        __builtin_amdgcn_sched_barrier(0);
        do_mfma32(af1, bv1, acc);
        asm volatile("s_waitcnt vmcnt(12)" ::: "memory");  // tile t+1 resident; t+2 in flight
        __builtin_amdgcn_s_barrier();                      // buf[t%3] recyclable
        cur = cur + 1; if (cur >= 3) cur -= 3;
    }
    // ---- t = NT-2: no staging; drain tile NT-1 ----
    {
        const bf16* ba = (const bf16*)lds + cur * BUF_ELE;
        const bf16* bb = ba + A_ELE;
        read_a(ba, aoff, slot0, af0);
        read_b(bb, boff, slot0, bv0);
        read_a(ba, aoff, slot1, af1);
        read_b(bb, boff, slot1, bv1);
        asm volatile("s_waitcnt lgkmcnt(12)" ::: "memory");
        __builtin_amdgcn_sched_barrier(0);
        do_mfma32(af0, bv0, acc);
        asm volatile("s_waitcnt lgkmcnt(0)" ::: "memory");
        __builtin_amdgcn_sched_barrier(0);
        do_mfma32(af1, bv1, acc);
        asm volatile("s_waitcnt vmcnt(0)" ::: "memory");
        __builtin_amdgcn_s_barrier();
        cur = cur + 1; if (cur >= 3) cur -= 3;
    }
    // ---- t = NT-1: compute only ----
    {
        const bf16* ba = (const bf16*)lds + cur * BUF_ELE;
        const bf16* bb = ba + A_ELE;
        read_a(ba, aoff, slot0, af0);
        read_b(bb, boff, slot0, bv0);
        read_a(ba, aoff, slot1, af1);
        read_b(bb, boff, slot1, bv1);
        asm volatile("s_waitcnt lgkmcnt(12)" ::: "memory");
        __builtin_amdgcn_sched_barrier(0);
        do_mfma32(af0, bv0, acc);
        asm volatile("s_waitcnt lgkmcnt(0)" ::: "memory");
        __builtin_amdgcn_sched_barrier(0);
        do_mfma32(af1, bv1, acc);
    }

    // ---- epilogue: C/D layout col = lane&15, row = (lane>>4)*4 + reg ----
    int row0 = tm * BM + wr * 64 + (lane >> 4) * 4;
    int col0 = tn * BN + wc * 128 + (lane & 15);
    if constexpr (OUT_BF16) {
        bf16* C = (bf16*)Cout;
        #pragma unroll
        for (int mi = 0; mi < 4; mi++)
            #pragma unroll
            for (int r = 0; r < 4; r++) {
                size_t base = (size_t)(row0 + mi * 16 + r) * N + col0;
                #pragma unroll
                for (int ni = 0; ni < 8; ni++)
                    C[base + ni * 16] = (bf16)acc[mi][ni][r];
            }
    } else {
        float* C = (float*)Cout;
        #pragma unroll
        for (int mi = 0; mi < 4; mi++)
            #pragma unroll
            for (int r = 0; r < 4; r++) {
                size_t base = (size_t)(row0 + mi * 16 + r) * N + col0;
                #pragma unroll
                for (int ni = 0; ni < 8; ni++)
                    C[base + ni * 16] = acc[mi][ni][r];
            }
    }
}

extern "C" void kernel_launch(void* const* d_in, const int* in_sizes, int n_in,
                              void* d_out, int out_size, void* d_ws, size_t ws_size,
                              hipStream_t stream) {
    const float* x0 = (const float*)d_in[0];
    const float* x1 = (const float*)d_in[1];
    const float* W0 = (const float*)d_in[2];
    const float* W1 = (const float*)d_in[3];
    const float* W2 = (const float*)d_in[4];

    char* ws = (char*)d_ws;
    const size_t MB = 1024 * 1024;
    bf16* Wt0 = (bf16*)(ws + 0 * MB);
    bf16* Wt1 = (bf16*)(ws + 8 * MB);
    bf16* Wt2 = (bf16*)(ws + 16 * MB);

    bf16 *Apk, *z1, *z2;
    if (ws_size >= 56 * MB) {
        Apk = (bf16*)(ws + 24 * MB);
        z1  = (bf16*)(ws + 40 * MB);
        z2  = Apk;                               // Apk dead after GEMM1
    } else {
        Apk = (bf16*)d_out;
        z1  = (bf16*)d_out + (size_t)M * K;      // second half of d_out
        z2  = (bf16*)(ws + 24 * MB);
    }

    prep_kernel<<<4096 + 3 * 4096, 256, 0, stream>>>(x0, x1, W0, W1, W2, Apk, Wt0, Wt1, Wt2);

    constexpr int grid = (M / BM) * (N / BN);    // 32 * 8 = 256
    gemm4w_kernel<true ><<<grid, 256, 0, stream>>>(Apk, Wt0, z1);
    gemm4w_kernel<true ><<<grid, 256, 0, stream>>>(z1,  Wt1, z2);
    gemm4w_kernel<false><<<grid, 256, 0, stream>>>(z2,  Wt2, (float*)d_out);
}